// Round 5
// baseline (248.563 us; speedup 1.0000x reference)
//
#include <hip/hip_runtime.h>
#include <hip/hip_bf16.h>

typedef unsigned short us;
typedef __attribute__((ext_vector_type(8))) __bf16 bf16x8;
typedef __attribute__((ext_vector_type(4))) float f32x4;

#define MFMA16(a, b, c) __builtin_amdgcn_mfma_f32_16x16x32_bf16(a, b, c, 0, 0, 0)

static __device__ __forceinline__ us f2bf(float f) {
  __hip_bfloat16 h = __float2bfloat16(f);
  return __builtin_bit_cast(us, h);
}

// async global->LDS, 16B per lane; LDS dest is wave-uniform base + lane*16
static __device__ __forceinline__ void gll16(const us* g, us* l) {
  __builtin_amdgcn_global_load_lds((const __attribute__((address_space(1))) void*)g,
                                   (__attribute__((address_space(3))) void*)l,
                                   16, 0, 0);
}

// ------------------------------------------------ prep: casts + rope table --
// blocks [0,8192): cast x; [8192,11264): cast w_qkv; [11264,12288): cast w_o;
// [12288,13312): rope table (4096 x 64).
__global__ void prep_kernel(const float* __restrict__ x, const float* __restrict__ wq,
                            const float* __restrict__ wo, us* __restrict__ xb,
                            us* __restrict__ wqb, us* __restrict__ wob,
                            float* __restrict__ ct, float* __restrict__ st) {
  const int blk = blockIdx.x;
  const int tid = threadIdx.x;
  if (blk < 12288) {
    const float* in;
    us* out;
    int i;
    if (blk < 8192)      { in = x;  out = xb;  i = blk * 256 + tid; }
    else if (blk < 11264){ in = wq; out = wqb; i = (blk - 8192) * 256 + tid; }
    else                 { in = wo; out = wob; i = (blk - 11264) * 256 + tid; }
    float4 v = ((const float4*)in)[i];
    ushort4 o;
    o.x = f2bf(v.x); o.y = f2bf(v.y); o.z = f2bf(v.z); o.w = f2bf(v.w);
    ((ushort4*)out)[i] = o;
  } else {
    int i = (blk - 12288) * 256 + tid;
    int t = i >> 6, d = i & 63;
    float ang = (float)t * exp2f((float)d * -0.20762050593046014f);
    float s, c;
    sincosf(ang, &s, &c);
    ct[i] = c;
    st[i] = s;
  }
}

// ------------------------------------------- GEMM1: qkv + RoPE + scatter ----
// R4-winning version, unchanged: 128^2 m97 structure, bf16 ld=130 V-epilogue
// -> 34.8KB LDS -> 4 blocks/CU (2->4 was +19%: cross-block waves hide each
// K-step's vmcnt(0)+barrier drain). 54.5us = ~945 TF = structure ceiling.
//
// A = xb [8192][1024], B = wqb [3072][1024] (out[m][n]=sum_k A[m,k]B[n,k])
// Wave col map: col(nt) = (wave>>1)*32 + (nt&1)*16 + (nt>>1)*64 -> RoPE partner
// d^64 is acc[mt][nt^2][r] in the SAME lane => register-only RoPE. q/k epilogue
// round-trips bf16 through LDS for uint4 coalesced stores.
__global__ __launch_bounds__(256, 4)
void qkv_rope_kernel(const us* __restrict__ A, const us* __restrict__ B,
                     const float* __restrict__ ctab, const float* __restrict__ stab,
                     us* __restrict__ qb, us* __restrict__ kb, us* __restrict__ vtb) {
  __shared__ __align__(16) char smem_raw[128 * 136 * 2]; // 34816B
  us* sA = (us*)smem_raw;
  us* sB = sA + 128 * 64;
  us* sCus = (us*)smem_raw;

  const int tid = threadIdx.x;
  const int lane = tid & 63;
  const int wave = tid >> 6;
  const int l15 = lane & 15;
  const int lq = lane >> 4;
  const int m0 = blockIdx.x * 128;
  const int n0 = blockIdx.y * 128;
  const int wm = (wave & 1) * 64;
  const int wn2 = (wave >> 1) * 32;

  f32x4 acc[4][4] = {};

  for (int k0 = 0; k0 < 1024; k0 += 64) {
    for (int i = 0; i < 4; ++i) {
      int c = wave * 4 + i;
      int P = c * 64 + lane;           // 16B slot index
      int row = P >> 3;                // 8 slots per 64-el row
      int cb = (P & 7) ^ (row & 7);    // xor-swizzle
      gll16(A + (size_t)(m0 + row) * 1024 + k0 + cb * 8, sA + c * 512);
      gll16(B + (size_t)(n0 + row) * 1024 + k0 + cb * 8, sB + c * 512);
    }
    __syncthreads();
#pragma unroll
    for (int kk = 0; kk < 64; kk += 32) {
      const int cbr = (kk + lq * 8) >> 3;
      bf16x8 av[4], bv[4];
#pragma unroll
      for (int mt = 0; mt < 4; ++mt) {
        int m = wm + mt * 16 + l15;
        av[mt] = *(const bf16x8*)(sA + (m * 8 + (cbr ^ (m & 7))) * 8);
      }
#pragma unroll
      for (int nt = 0; nt < 4; ++nt) {
        int n = wn2 + (nt & 1) * 16 + (nt >> 1) * 64 + l15;
        bv[nt] = *(const bf16x8*)(sB + (n * 8 + (cbr ^ (n & 7))) * 8);
      }
#pragma unroll
      for (int mt = 0; mt < 4; ++mt)
#pragma unroll
        for (int nt = 0; nt < 4; ++nt)
          acc[mt][nt] = MFMA16(av[mt], bv[nt], acc[mt][nt]);
    }
    __syncthreads();
  }

  const int b = m0 >> 12;
  const int t0 = m0 & 4095;
  const int which = blockIdx.y >> 3;
  const int h = blockIdx.y & 7;

  if (which < 2) {
    // register RoPE -> bf16 LDS tile (ld=136: rows 16B-aligned) -> uint4 stores
    us* outp = (which == 0) ? qb : kb;
    const size_t obase = ((size_t)(b * 8 + h)) * 4096 * 128;
#pragma unroll
    for (int mt = 0; mt < 4; ++mt)
#pragma unroll
      for (int r = 0; r < 4; ++r) {
        const int row = wm + mt * 16 + lq * 4 + r;
        const int tg = t0 + row;
        const float* cp = ctab + tg * 64 + wn2 + l15;
        const float* sp = stab + tg * 64 + wn2 + l15;
        const float c0 = cp[0], c1 = cp[16], s0 = sp[0], s1 = sp[16];
#pragma unroll
        for (int nt = 0; nt < 4; ++nt) {
          float xv = acc[mt][nt][r];
          float xp = acc[mt][nt ^ 2][r];
          float rot = (nt < 2) ? -xp : xp;
          float y = xv * ((nt & 1) ? c1 : c0) + rot * ((nt & 1) ? s1 : s0);
          sCus[row * 136 + wn2 + (nt & 1) * 16 + (nt >> 1) * 64 + l15] = f2bf(y);
        }
      }
    __syncthreads();
    for (int r = 0; r < 8; ++r) {
      int row = (tid >> 4) + r * 16;
      int col = (tid & 15) * 8;
      uint4 v = *(const uint4*)(sCus + row * 136 + col);
      *(uint4*)(outp + obase + (size_t)(t0 + row) * 128 + col) = v;
    }
  } else {
    // V: bf16 LDS transpose, ld=130 (odd stride -> ~4-way column reads)
#pragma unroll
    for (int mt = 0; mt < 4; ++mt)
#pragma unroll
      for (int nt = 0; nt < 4; ++nt) {
        const int col = wn2 + (nt & 1) * 16 + (nt >> 1) * 64 + l15;
#pragma unroll
        for (int r = 0; r < 4; ++r)
          sCus[(wm + mt * 16 + lq * 4 + r) * 130 + col] = f2bf(acc[mt][nt][r]);
      }
    __syncthreads();
    for (int r = 0; r < 8; ++r) {
      int d = (tid >> 4) + r * 16;
      int tl0 = (tid & 15) * 8;
      union { us u[8]; uint4 v; } tmp;
#pragma unroll
      for (int j = 0; j < 8; ++j)
        tmp.u[j] = sCus[(tl0 + j) * 130 + d];
      *(uint4*)(vtb + ((size_t)((b * 8 + h) * 128 + d)) * 4096 + t0 + tl0) = tmp.v;
    }
  }
}

// --------------------------------------------------- flash attention --------
// R5: QBLK 128->64, single-buffered K/V. LDS 80KB->40KB (sK 16K + sV 16K +
// sP 8K) -> 4 blocks/CU; grid (64,8,2)=1024 = exactly 4/CU, zero tail.
// Rationale: flash is latency/barrier-bound (MFMA floor 9us, LDS-pipe floor
// ~20us, observed ~45-54us). At 2 blocks/CU each tile's vmcnt(0) drain had
// one co-resident block to hide behind; 4-way block TLP hides both the
// (now exposed) single-buffer staging wait and the barrier drains — the
// same mechanism that gave qkv +19% in R4. QBLK==KVBLK also means exactly
// ONE causal tile and ONE window tile (less masked waste, total MFMA -10%).
// Per-wave: 16 q-rows (wm2=wave*16), per tile: 16 QK + 18 PV MFMA.
// MASK: 0=none, 1=window-low (jt==jtmin, t0>=512), 2=causal (jt==jtmax).
template <int MASK>
__device__ __forceinline__ void p_write(f32x4 (&s)[4], us* __restrict__ sP,
                                        int t0, int tj0, int wm2, int lq, int l15) {
  const float C2 = 0.08838834764831845f * 1.4426950408889634f; // scale * log2(e)
#pragma unroll
  for (int nt = 0; nt < 4; ++nt) {
    const int jg = tj0 + nt * 16 + l15;
    const int cb = (nt * 16 + l15) >> 3; // 16B col-block 0..7
    const int co = l15 & 7;
#pragma unroll
    for (int r = 0; r < 4; ++r) {
      const int rowl = wm2 + lq * 4 + r;
      float v = s[nt][r];
      if (MASK == 1) v = (jg + 512 >= t0 + rowl) ? v : -3.0e38f;
      if (MASK == 2) v = (jg <= t0 + rowl) ? v : -3.0e38f;
      sP[rowl * 64 + ((cb ^ (rowl & 7)) * 8) + co] = f2bf(exp2f(v * C2));
    }
  }
}

__global__ __launch_bounds__(256, 4)
void flash_kernel(const us* __restrict__ qg, const us* __restrict__ kg,
                  const us* __restrict__ vg, us* __restrict__ ao) {
  __shared__ us smem[20480]; // 40960 B = 160KB/4 exactly
  us* sK = smem;             // 64 j x 128 d swizzled (single buffer)
  us* sV = smem + 8192;      // 128 d x 64 j swizzled (V^T, single buffer)
  us* sP = smem + 16384;     // 64 x 64, XOR-block swizzle on (row&7)

  const int tid = threadIdx.x;
  const int lane = tid & 63;
  const int wave = tid >> 6;
  const int l15 = lane & 15;
  const int lq = lane >> 4;
  const int qx = blockIdx.x;
  const int h = blockIdx.y;
  const int b = blockIdx.z;
  const int t0 = qx * 64;
  const size_t bh = (size_t)(b * 8 + h);
  const int wm2 = wave * 16;

  // Q fragments direct to registers (A-layout: A[m=lane&15][k=lq*8+j])
  bf16x8 qf[4];
#pragma unroll
  for (int ks = 0; ks < 4; ++ks)
    qf[ks] = *(const bf16x8*)(qg + (bh * 4096 + t0 + wm2 + l15) * 128 +
                              ks * 32 + lq * 8);

  // all-ones B-fragment for the row-sum column
  union { us u[8]; bf16x8 v; } one_u;
#pragma unroll
  for (int i = 0; i < 8; ++i) one_u.u[i] = 0x3F80;
  const bf16x8 vone = one_u.v;

  f32x4 o[9] = {}; // [0..7]=O columns, [8]=row-sum l

  const int lo = t0 - 512;
  const int jtmin = (lo <= 0) ? 0 : (lo >> 6);
  const int jtmax = t0 >> 6;
  const bool wmask = (t0 >= 512);

  auto stage = [&](int jt) {
    const int tj0 = jt * 64;
    for (int i = 0; i < 4; ++i) {
      int c = wave * 4 + i;
      int P = c * 64 + lane;
      int rowK = P >> 4;                 // 16 slots per 128-el row
      int cbK = (P & 15) ^ (rowK & 15);
      gll16(kg + (bh * 4096 + tj0 + rowK) * 128 + cbK * 8, sK + c * 512);
      int rowV = P >> 3;                 // 8 slots per 64-el row
      int cbV = (P & 7) ^ (rowV & 7);
      gll16(vg + (bh * 128 + rowV) * 4096 + tj0 + cbV * 8, sV + c * 512);
    }
  };

  for (int jt = jtmin; jt <= jtmax; ++jt) {
    __syncthreads(); // all waves done reading previous tile
    stage(jt);
    __syncthreads(); // vmcnt(0) drain -> tile resident (hidden by 4-block TLP)

    const int tj0 = jt * 64;

    // S = Q K^T  (each wave: 16 q-rows x 64 keys)
    f32x4 s[4] = {};
#pragma unroll
    for (int ks = 0; ks < 4; ++ks) {
      const int cbr = ks * 4 + lq;
#pragma unroll
      for (int nt = 0; nt < 4; ++nt) {
        int n = nt * 16 + l15;
        bf16x8 bk = *(const bf16x8*)(sK + (n * 16 + (cbr ^ (n & 15))) * 8);
        s[nt] = MFMA16(qf[ks], bk, s[nt]);
      }
    }

    // P = exp2(S*C2) with mask -> sP (own rows; no cross-lane ops, no barrier)
    if (jt == jtmax)                p_write<2>(s, sP, t0, tj0, wm2, lq, l15);
    else if (wmask && jt == jtmin)  p_write<1>(s, sP, t0, tj0, wm2, lq, l15);
    else                            p_write<0>(s, sP, t0, tj0, wm2, lq, l15);

    // O += P V ; l += P 1  (A = sP own rows; in-order DS pipe covers RAW)
#pragma unroll
    for (int ks = 0; ks < 2; ++ks) {
      bf16x8 ap = *(const bf16x8*)(sP + (wm2 + l15) * 64 +
                                   (((ks * 4 + lq) ^ (l15 & 7)) * 8));
#pragma unroll
      for (int dt = 0; dt < 8; ++dt) {
        int dd = dt * 16 + l15;
        bf16x8 bv = *(const bf16x8*)(sV + (dd * 8 + ((ks * 4 + lq) ^ (dd & 7))) * 8);
        o[dt] = MFMA16(ap, bv, o[dt]);
      }
      o[8] = MFMA16(ap, vone, o[8]);
    }
  }

  // epilogue: O/l -> ao [b*4096+t][h*128+d] bf16
#pragma unroll
  for (int r = 0; r < 4; ++r) {
    const float inv = 1.0f / o[8][r];
    const int rowl = wm2 + lq * 4 + r;
    const size_t base = ((size_t)b * 4096 + t0 + rowl) * 1024 + h * 128;
#pragma unroll
    for (int dt = 0; dt < 8; ++dt)
      ao[base + dt * 16 + l15] = f2bf(o[dt][r] * inv);
  }
}

// ------------------------------------------------ GEMM3: out = ao @ w_o^T ---
__global__ __launch_bounds__(256, 2)
void out_proj_kernel(const us* __restrict__ A, const us* __restrict__ B, float* __restrict__ C) {
  __shared__ us sA[128 * 64];
  __shared__ us sB[128 * 64];
  const int tid = threadIdx.x;
  const int lane = tid & 63;
  const int wave = tid >> 6;
  const int l15 = lane & 15;
  const int lq = lane >> 4;
  const int m0 = blockIdx.x * 128;
  const int n0 = blockIdx.y * 128;
  const int wm = (wave & 1) * 64;
  const int wn = (wave >> 1) * 64;
  f32x4 acc[4][4] = {};
  for (int k0 = 0; k0 < 1024; k0 += 64) {
    for (int i = 0; i < 4; ++i) {
      int c = wave * 4 + i;
      int P = c * 64 + lane;
      int row = P >> 3;
      int cb = (P & 7) ^ (row & 7);
      gll16(A + (size_t)(m0 + row) * 1024 + k0 + cb * 8, sA + c * 512);
      gll16(B + (size_t)(n0 + row) * 1024 + k0 + cb * 8, sB + c * 512);
    }
    __syncthreads();
#pragma unroll
    for (int kk = 0; kk < 64; kk += 32) {
      const int cbr = (kk + lq * 8) >> 3;
      bf16x8 av[4], bv[4];
#pragma unroll
      for (int mt = 0; mt < 4; ++mt) {
        int m = wm + mt * 16 + l15;
        av[mt] = *(const bf16x8*)(sA + (m * 8 + (cbr ^ (m & 7))) * 8);
      }
#pragma unroll
      for (int nt = 0; nt < 4; ++nt) {
        int n = wn + nt * 16 + l15;
        bv[nt] = *(const bf16x8*)(sB + (n * 8 + (cbr ^ (n & 7))) * 8);
      }
#pragma unroll
      for (int mt = 0; mt < 4; ++mt)
#pragma unroll
        for (int nt = 0; nt < 4; ++nt)
          acc[mt][nt] = MFMA16(av[mt], bv[nt], acc[mt][nt]);
    }
    __syncthreads();
  }
#pragma unroll
  for (int mt = 0; mt < 4; ++mt)
#pragma unroll
    for (int nt = 0; nt < 4; ++nt)
#pragma unroll
      for (int r = 0; r < 4; ++r)
        C[(size_t)(m0 + wm + mt * 16 + lq * 4 + r) * 1024 + (n0 + wn + nt * 16 + l15)] =
            acc[mt][nt][r];
}

// ---------------------------------------------------------------- launch ----
extern "C" void kernel_launch(void* const* d_in, const int* in_sizes, int n_in,
                              void* d_out, int out_size, void* d_ws, size_t ws_size,
                              hipStream_t stream) {
  const float* x     = (const float*)d_in[0];  // [2,4096,1024]
  const float* w_qkv = (const float*)d_in[1];  // [3072,1024]
  const float* w_o   = (const float*)d_in[2];  // [1024,1024]
  float* out = (float*)d_out;                  // [2,4096,1024] fp32

  us* xb  = (us*)d_ws;                          // 8192*1024
  us* wqb = xb  + (size_t)8192 * 1024;          // 3072*1024
  us* wob = wqb + (size_t)3072 * 1024;          // 1024*1024
  us* qb  = wob + (size_t)1024 * 1024;          // [2][8][4096][128]
  us* kb  = qb  + (size_t)2 * 8 * 4096 * 128;
  us* vtb = kb  + (size_t)2 * 8 * 4096 * 128;   // [2][8][128][4096]
  us* aob = vtb + (size_t)2 * 8 * 4096 * 128;   // 8192*1024
  float* ctab = (float*)(aob + (size_t)8192 * 1024); // [4096][64]
  float* stab = ctab + (size_t)4096 * 64;

  prep_kernel<<<13312, 256, 0, stream>>>(x, w_qkv, w_o, xb, wqb, wob, ctab, stab);
  qkv_rope_kernel<<<dim3(64, 24), 256, 0, stream>>>(xb, wqb, ctab, stab, qb, kb, vtb);
  flash_kernel<<<dim3(64, 8, 2), 256, 0, stream>>>(qb, kb, vtb, aob);
  out_proj_kernel<<<dim3(64, 8), 256, 0, stream>>>(aob, wob, out);
}

// Round 7
// 214.464 us; speedup vs baseline: 1.1590x; 1.1590x over previous
//
#include <hip/hip_runtime.h>
#include <hip/hip_bf16.h>

typedef unsigned short us;
typedef __attribute__((ext_vector_type(8))) __bf16 bf16x8;
typedef __attribute__((ext_vector_type(4))) float f32x4;

#define MFMA16(a, b, c) __builtin_amdgcn_mfma_f32_16x16x32_bf16(a, b, c, 0, 0, 0)

static __device__ __forceinline__ us f2bf(float f) {
  __hip_bfloat16 h = __float2bfloat16(f);
  return __builtin_bit_cast(us, h);
}

// async global->LDS, 16B per lane; LDS dest is wave-uniform base + lane*16
static __device__ __forceinline__ void gll16(const us* g, us* l) {
  __builtin_amdgcn_global_load_lds((const __attribute__((address_space(1))) void*)g,
                                   (__attribute__((address_space(3))) void*)l,
                                   16, 0, 0);
}

// ------------------------------------------------ prep: casts + rope table --
// blocks [0,8192): cast x; [8192,11264): cast w_qkv; [11264,12288): cast w_o;
// [12288,13312): rope table (4096 x 64).
__global__ void prep_kernel(const float* __restrict__ x, const float* __restrict__ wq,
                            const float* __restrict__ wo, us* __restrict__ xb,
                            us* __restrict__ wqb, us* __restrict__ wob,
                            float* __restrict__ ct, float* __restrict__ st) {
  const int blk = blockIdx.x;
  const int tid = threadIdx.x;
  if (blk < 12288) {
    const float* in;
    us* out;
    int i;
    if (blk < 8192)      { in = x;  out = xb;  i = blk * 256 + tid; }
    else if (blk < 11264){ in = wq; out = wqb; i = (blk - 8192) * 256 + tid; }
    else                 { in = wo; out = wob; i = (blk - 11264) * 256 + tid; }
    float4 v = ((const float4*)in)[i];
    ushort4 o;
    o.x = f2bf(v.x); o.y = f2bf(v.y); o.z = f2bf(v.z); o.w = f2bf(v.w);
    ((ushort4*)out)[i] = o;
  } else {
    int i = (blk - 12288) * 256 + tid;
    int t = i >> 6, d = i & 63;
    float ang = (float)t * exp2f((float)d * -0.20762050593046014f);
    float s, c;
    sincosf(ang, &s, &c);
    ct[i] = c;
    st[i] = s;
  }
}

// ------------------------------------------- GEMM1: qkv + RoPE + scatter ----
// R4-winning version, unchanged: 128^2 m97 structure, bf16 ld=130 V-epilogue
// -> 34.8KB LDS -> 4 blocks/CU (2->4 was +19%: cross-block waves hide each
// K-step's vmcnt(0)+barrier drain). 54.5us = ~945 TF = structure ceiling.
//
// A = xb [8192][1024], B = wqb [3072][1024] (out[m][n]=sum_k A[m,k]B[n,k])
// Wave col map: col(nt) = (wave>>1)*32 + (nt&1)*16 + (nt>>1)*64 -> RoPE partner
// d^64 is acc[mt][nt^2][r] in the SAME lane => register-only RoPE. q/k epilogue
// round-trips bf16 through LDS for uint4 coalesced stores.
__global__ __launch_bounds__(256, 4)
void qkv_rope_kernel(const us* __restrict__ A, const us* __restrict__ B,
                     const float* __restrict__ ctab, const float* __restrict__ stab,
                     us* __restrict__ qb, us* __restrict__ kb, us* __restrict__ vtb) {
  __shared__ __align__(16) char smem_raw[128 * 136 * 2]; // 34816B
  us* sA = (us*)smem_raw;
  us* sB = sA + 128 * 64;
  us* sCus = (us*)smem_raw;

  const int tid = threadIdx.x;
  const int lane = tid & 63;
  const int wave = tid >> 6;
  const int l15 = lane & 15;
  const int lq = lane >> 4;
  const int m0 = blockIdx.x * 128;
  const int n0 = blockIdx.y * 128;
  const int wm = (wave & 1) * 64;
  const int wn2 = (wave >> 1) * 32;

  f32x4 acc[4][4] = {};

  for (int k0 = 0; k0 < 1024; k0 += 64) {
    for (int i = 0; i < 4; ++i) {
      int c = wave * 4 + i;
      int P = c * 64 + lane;           // 16B slot index
      int row = P >> 3;                // 8 slots per 64-el row
      int cb = (P & 7) ^ (row & 7);    // xor-swizzle
      gll16(A + (size_t)(m0 + row) * 1024 + k0 + cb * 8, sA + c * 512);
      gll16(B + (size_t)(n0 + row) * 1024 + k0 + cb * 8, sB + c * 512);
    }
    __syncthreads();
#pragma unroll
    for (int kk = 0; kk < 64; kk += 32) {
      const int cbr = (kk + lq * 8) >> 3;
      bf16x8 av[4], bv[4];
#pragma unroll
      for (int mt = 0; mt < 4; ++mt) {
        int m = wm + mt * 16 + l15;
        av[mt] = *(const bf16x8*)(sA + (m * 8 + (cbr ^ (m & 7))) * 8);
      }
#pragma unroll
      for (int nt = 0; nt < 4; ++nt) {
        int n = wn2 + (nt & 1) * 16 + (nt >> 1) * 64 + l15;
        bv[nt] = *(const bf16x8*)(sB + (n * 8 + (cbr ^ (n & 7))) * 8);
      }
#pragma unroll
      for (int mt = 0; mt < 4; ++mt)
#pragma unroll
        for (int nt = 0; nt < 4; ++nt)
          acc[mt][nt] = MFMA16(av[mt], bv[nt], acc[mt][nt]);
    }
    __syncthreads();
  }

  const int b = m0 >> 12;
  const int t0 = m0 & 4095;
  const int which = blockIdx.y >> 3;
  const int h = blockIdx.y & 7;

  if (which < 2) {
    // register RoPE -> bf16 LDS tile (ld=136: rows 16B-aligned) -> uint4 stores
    us* outp = (which == 0) ? qb : kb;
    const size_t obase = ((size_t)(b * 8 + h)) * 4096 * 128;
#pragma unroll
    for (int mt = 0; mt < 4; ++mt)
#pragma unroll
      for (int r = 0; r < 4; ++r) {
        const int row = wm + mt * 16 + lq * 4 + r;
        const int tg = t0 + row;
        const float* cp = ctab + tg * 64 + wn2 + l15;
        const float* sp = stab + tg * 64 + wn2 + l15;
        const float c0 = cp[0], c1 = cp[16], s0 = sp[0], s1 = sp[16];
#pragma unroll
        for (int nt = 0; nt < 4; ++nt) {
          float xv = acc[mt][nt][r];
          float xp = acc[mt][nt ^ 2][r];
          float rot = (nt < 2) ? -xp : xp;
          float y = xv * ((nt & 1) ? c1 : c0) + rot * ((nt & 1) ? s1 : s0);
          sCus[row * 136 + wn2 + (nt & 1) * 16 + (nt >> 1) * 64 + l15] = f2bf(y);
        }
      }
    __syncthreads();
    for (int r = 0; r < 8; ++r) {
      int row = (tid >> 4) + r * 16;
      int col = (tid & 15) * 8;
      uint4 v = *(const uint4*)(sCus + row * 136 + col);
      *(uint4*)(outp + obase + (size_t)(t0 + row) * 128 + col) = v;
    }
  } else {
    // V: bf16 LDS transpose, ld=130 (odd stride -> ~4-way column reads)
#pragma unroll
    for (int mt = 0; mt < 4; ++mt)
#pragma unroll
      for (int nt = 0; nt < 4; ++nt) {
        const int col = wn2 + (nt & 1) * 16 + (nt >> 1) * 64 + l15;
#pragma unroll
        for (int r = 0; r < 4; ++r)
          sCus[(wm + mt * 16 + lq * 4 + r) * 130 + col] = f2bf(acc[mt][nt][r]);
      }
    __syncthreads();
    for (int r = 0; r < 8; ++r) {
      int d = (tid >> 4) + r * 16;
      int tl0 = (tid & 15) * 8;
      union { us u[8]; uint4 v; } tmp;
#pragma unroll
      for (int j = 0; j < 8; ++j)
        tmp.u[j] = sCus[(tl0 + j) * 130 + d];
      *(uint4*)(vtb + ((size_t)((b * 8 + h) * 128 + d)) * 4096 + t0 + tl0) = tmp.v;
    }
  }
}

// --------------------------------------------------- flash attention --------
// R7 = R6 resubmitted (infra failure, no data): QBLK=128 + dbuf (minimal
// traffic — R5's QBLK=64/single-buf was BW-bound at FETCH 240MB), but 512
// THREADS: 8 waves x 16 q-rows. Same 80KB LDS -> still 2 blocks/CU, but 16
// waves/CU (4/SIMD) instead of 8 — doubles wave TLP to hide the per-tile
// vmcnt(0)+barrier drain WITHOUT changing global traffic. Per-wave regs
// ~100 <= 128 cap from (512,4) [2048-reg pool / 4 waves/EU].
// sP 128x64 XOR-block-swizzled; no running max (window scores bounded);
// l via 9th PV column against all-ones B-frag.
// MASK: 0=none, 1=window-low (first TWO tiles, t0>=512), 2=causal (last TWO).
template <int MASK>
__device__ __forceinline__ void p_write(f32x4 (&s)[4], us* __restrict__ sP,
                                        int t0, int tj0, int wm2, int lq, int l15) {
  const float C2 = 0.08838834764831845f * 1.4426950408889634f; // scale * log2(e)
#pragma unroll
  for (int nt = 0; nt < 4; ++nt) {
    const int jg = tj0 + nt * 16 + l15;
    const int cb = (nt * 16 + l15) >> 3; // 16B col-block 0..7
    const int co = l15 & 7;
#pragma unroll
    for (int r = 0; r < 4; ++r) {
      const int rowl = wm2 + lq * 4 + r;
      float v = s[nt][r];
      if (MASK == 1) v = (jg + 512 >= t0 + rowl) ? v : -3.0e38f;
      if (MASK == 2) v = (jg <= t0 + rowl) ? v : -3.0e38f;
      sP[rowl * 64 + ((cb ^ (rowl & 7)) * 8) + co] = f2bf(exp2f(v * C2));
    }
  }
}

// grid (qx=32, h=8, b=2) = 512 blocks x 512 thr = 2 blocks/CU, zero tail.
__global__ __launch_bounds__(512, 4)
void flash_kernel(const us* __restrict__ qg, const us* __restrict__ kg,
                  const us* __restrict__ vg, us* __restrict__ ao) {
  __shared__ us smem[40960]; // 81920 B total = 160KB/2 exactly
  us* sK = smem;             // dbuf 2 x (64 j x 128 d) swizzled
  us* sV = smem + 16384;     // dbuf 2 x (128 d x 64 j) swizzled (V^T)
  us* sP = smem + 32768;     // 128 x 64, XOR-block swizzle on (row&7)

  const int tid = threadIdx.x;
  const int lane = tid & 63;
  const int wave = tid >> 6;  // 0..7
  const int l15 = lane & 15;
  const int lq = lane >> 4;
  const int qx = blockIdx.x;
  const int h = blockIdx.y;
  const int b = blockIdx.z;
  const int t0 = qx * 128;
  const size_t bh = (size_t)(b * 8 + h);
  const int wm2 = wave * 16;  // 16 q-rows per wave

  // Q fragments direct to registers (A-layout: A[m=lane&15][k=lq*8+j])
  bf16x8 qf[4];
#pragma unroll
  for (int ks = 0; ks < 4; ++ks)
    qf[ks] = *(const bf16x8*)(qg + (bh * 4096 + t0 + wm2 + l15) * 128 +
                              ks * 32 + lq * 8);

  // all-ones B-fragment for the row-sum column
  union { us u[8]; bf16x8 v; } one_u;
#pragma unroll
  for (int i = 0; i < 8; ++i) one_u.u[i] = 0x3F80;
  const bf16x8 vone = one_u.v;

  f32x4 o[9] = {}; // [0..7]=O columns, [8]=row-sum l

  const int lo = t0 - 512;
  const int jtmin = (lo <= 0) ? 0 : (lo >> 6);
  const int jtmax = (t0 + 127) >> 6;
  const bool wmask = (t0 >= 512);

  auto stage = [&](int jt, int buf) {
    const int tj0 = jt * 64;
    us* dK = sK + buf * 8192;
    us* dV = sV + buf * 8192;
    for (int i = 0; i < 2; ++i) {
      int c = wave * 2 + i;              // 16 chunks over 8 waves
      int P = c * 64 + lane;
      int rowK = P >> 4;                 // 16 slots per 128-el row
      int cbK = (P & 15) ^ (rowK & 15);
      gll16(kg + (bh * 4096 + tj0 + rowK) * 128 + cbK * 8, dK + c * 512);
      int rowV = P >> 3;                 // 8 slots per 64-el row
      int cbV = (P & 7) ^ (rowV & 7);
      gll16(vg + (bh * 128 + rowV) * 4096 + tj0 + cbV * 8, dV + c * 512);
    }
  };

  stage(jtmin, 0);
  int cur = 0;

  for (int jt = jtmin; jt <= jtmax; ++jt) {
    __syncthreads(); // drains prefetch of buf[cur] (issued a full tile ago)
    if (jt < jtmax) stage(jt + 1, cur ^ 1);

    const int tj0 = jt * 64;
    const us* sKc = sK + cur * 8192;
    const us* sVc = sV + cur * 8192;

    // S = Q K^T  (each wave: 16 q-rows x 64 keys)
    f32x4 s[4] = {};
#pragma unroll
    for (int ks = 0; ks < 4; ++ks) {
      const int cbr = ks * 4 + lq;
#pragma unroll
      for (int nt = 0; nt < 4; ++nt) {
        int n = nt * 16 + l15;
        bf16x8 bk = *(const bf16x8*)(sKc + (n * 16 + (cbr ^ (n & 15))) * 8);
        s[nt] = MFMA16(qf[ks], bk, s[nt]);
      }
    }

    // P = exp2(S*C2) with mask -> sP (own rows; no cross-lane ops, no barrier)
    if (jt >= jtmax - 1)               p_write<2>(s, sP, t0, tj0, wm2, lq, l15);
    else if (wmask && jt <= jtmin + 1) p_write<1>(s, sP, t0, tj0, wm2, lq, l15);
    else                               p_write<0>(s, sP, t0, tj0, wm2, lq, l15);

    // O += P V ; l += P 1  (A = sP own rows; in-order DS pipe covers RAW)
#pragma unroll
    for (int ks = 0; ks < 2; ++ks) {
      bf16x8 ap = *(const bf16x8*)(sP + (wm2 + l15) * 64 +
                                   (((ks * 4 + lq) ^ (l15 & 7)) * 8));
#pragma unroll
      for (int dt = 0; dt < 8; ++dt) {
        int dd = dt * 16 + l15;
        bf16x8 bv = *(const bf16x8*)(sVc + (dd * 8 + ((ks * 4 + lq) ^ (dd & 7))) * 8);
        o[dt] = MFMA16(ap, bv, o[dt]);
      }
      o[8] = MFMA16(ap, vone, o[8]);
    }
    cur ^= 1;
  }

  // epilogue: O/l -> ao [b*4096+t][h*128+d] bf16
#pragma unroll
  for (int r = 0; r < 4; ++r) {
    const float inv = 1.0f / o[8][r];
    const int rowl = wm2 + lq * 4 + r;
    const size_t base = ((size_t)b * 4096 + t0 + rowl) * 1024 + h * 128;
#pragma unroll
    for (int dt = 0; dt < 8; ++dt)
      ao[base + dt * 16 + l15] = f2bf(o[dt][r] * inv);
  }
}

// ------------------------------------------------ GEMM3: out = ao @ w_o^T ---
__global__ __launch_bounds__(256, 2)
void out_proj_kernel(const us* __restrict__ A, const us* __restrict__ B, float* __restrict__ C) {
  __shared__ us sA[128 * 64];
  __shared__ us sB[128 * 64];
  const int tid = threadIdx.x;
  const int lane = tid & 63;
  const int wave = tid >> 6;
  const int l15 = lane & 15;
  const int lq = lane >> 4;
  const int m0 = blockIdx.x * 128;
  const int n0 = blockIdx.y * 128;
  const int wm = (wave & 1) * 64;
  const int wn = (wave >> 1) * 64;
  f32x4 acc[4][4] = {};
  for (int k0 = 0; k0 < 1024; k0 += 64) {
    for (int i = 0; i < 4; ++i) {
      int c = wave * 4 + i;
      int P = c * 64 + lane;
      int row = P >> 3;
      int cb = (P & 7) ^ (row & 7);
      gll16(A + (size_t)(m0 + row) * 1024 + k0 + cb * 8, sA + c * 512);
      gll16(B + (size_t)(n0 + row) * 1024 + k0 + cb * 8, sB + c * 512);
    }
    __syncthreads();
#pragma unroll
    for (int kk = 0; kk < 64; kk += 32) {
      const int cbr = (kk + lq * 8) >> 3;
      bf16x8 av[4], bv[4];
#pragma unroll
      for (int mt = 0; mt < 4; ++mt) {
        int m = wm + mt * 16 + l15;
        av[mt] = *(const bf16x8*)(sA + (m * 8 + (cbr ^ (m & 7))) * 8);
      }
#pragma unroll
      for (int nt = 0; nt < 4; ++nt) {
        int n = wn + nt * 16 + l15;
        bv[nt] = *(const bf16x8*)(sB + (n * 8 + (cbr ^ (n & 7))) * 8);
      }
#pragma unroll
      for (int mt = 0; mt < 4; ++mt)
#pragma unroll
        for (int nt = 0; nt < 4; ++nt)
          acc[mt][nt] = MFMA16(av[mt], bv[nt], acc[mt][nt]);
    }
    __syncthreads();
  }
#pragma unroll
  for (int mt = 0; mt < 4; ++mt)
#pragma unroll
    for (int nt = 0; nt < 4; ++nt)
#pragma unroll
      for (int r = 0; r < 4; ++r)
        C[(size_t)(m0 + wm + mt * 16 + lq * 4 + r) * 1024 + (n0 + wn + nt * 16 + l15)] =
            acc[mt][nt][r];
}

// ---------------------------------------------------------------- launch ----
extern "C" void kernel_launch(void* const* d_in, const int* in_sizes, int n_in,
                              void* d_out, int out_size, void* d_ws, size_t ws_size,
                              hipStream_t stream) {
  const float* x     = (const float*)d_in[0];  // [2,4096,1024]
  const float* w_qkv = (const float*)d_in[1];  // [3072,1024]
  const float* w_o   = (const float*)d_in[2];  // [1024,1024]
  float* out = (float*)d_out;                  // [2,4096,1024] fp32

  us* xb  = (us*)d_ws;                          // 8192*1024
  us* wqb = xb  + (size_t)8192 * 1024;          // 3072*1024
  us* wob = wqb + (size_t)3072 * 1024;          // 1024*1024
  us* qb  = wob + (size_t)1024 * 1024;          // [2][8][4096][128]
  us* kb  = qb  + (size_t)2 * 8 * 4096 * 128;
  us* vtb = kb  + (size_t)2 * 8 * 4096 * 128;   // [2][8][128][4096]
  us* aob = vtb + (size_t)2 * 8 * 4096 * 128;   // 8192*1024
  float* ctab = (float*)(aob + (size_t)8192 * 1024); // [4096][64]
  float* stab = ctab + (size_t)4096 * 64;

  prep_kernel<<<13312, 256, 0, stream>>>(x, w_qkv, w_o, xb, wqb, wob, ctab, stab);
  qkv_rope_kernel<<<dim3(64, 24), 256, 0, stream>>>(xb, wqb, ctab, stab, qb, kb, vtb);
  flash_kernel<<<dim3(32, 8, 2), 512, 0, stream>>>(qb, kb, vtb, aob);
  out_proj_kernel<<<dim3(64, 8), 256, 0, stream>>>(aob, wob, out);
}

// Round 8
// 206.570 us; speedup vs baseline: 1.2033x; 1.0382x over previous
//
#include <hip/hip_runtime.h>
#include <hip/hip_bf16.h>

typedef unsigned short us;
typedef __attribute__((ext_vector_type(8))) __bf16 bf16x8;
typedef __attribute__((ext_vector_type(4))) float f32x4;

#define MFMA16(a, b, c) __builtin_amdgcn_mfma_f32_16x16x32_bf16(a, b, c, 0, 0, 0)

static __device__ __forceinline__ us f2bf(float f) {
  __hip_bfloat16 h = __float2bfloat16(f);
  return __builtin_bit_cast(us, h);
}

// async global->LDS, 16B per lane; LDS dest is wave-uniform base + lane*16
static __device__ __forceinline__ void gll16(const us* g, us* l) {
  __builtin_amdgcn_global_load_lds((const __attribute__((address_space(1))) void*)g,
                                   (__attribute__((address_space(3))) void*)l,
                                   16, 0, 0);
}

// ------------------------------------------------ prep: casts + rope table --
// blocks [0,8192): cast x; [8192,11264): cast w_qkv; [11264,12288): cast w_o;
// [12288,13312): rope table (4096 x 64).
__global__ void prep_kernel(const float* __restrict__ x, const float* __restrict__ wq,
                            const float* __restrict__ wo, us* __restrict__ xb,
                            us* __restrict__ wqb, us* __restrict__ wob,
                            float* __restrict__ ct, float* __restrict__ st) {
  const int blk = blockIdx.x;
  const int tid = threadIdx.x;
  if (blk < 12288) {
    const float* in;
    us* out;
    int i;
    if (blk < 8192)      { in = x;  out = xb;  i = blk * 256 + tid; }
    else if (blk < 11264){ in = wq; out = wqb; i = (blk - 8192) * 256 + tid; }
    else                 { in = wo; out = wob; i = (blk - 11264) * 256 + tid; }
    float4 v = ((const float4*)in)[i];
    ushort4 o;
    o.x = f2bf(v.x); o.y = f2bf(v.y); o.z = f2bf(v.z); o.w = f2bf(v.w);
    ((ushort4*)out)[i] = o;
  } else {
    int i = (blk - 12288) * 256 + tid;
    int t = i >> 6, d = i & 63;
    float ang = (float)t * exp2f((float)d * -0.20762050593046014f);
    float s, c;
    sincosf(ang, &s, &c);
    ct[i] = c;
    st[i] = s;
  }
}

// ------------------------------------------- GEMM1: qkv + RoPE + scatter ----
// R4-winning version, unchanged: 128^2 m97 structure, bf16 ld=130 V-epilogue
// -> 34.8KB LDS -> 4 blocks/CU (2->4 was +19%: cross-block waves hide each
// K-step's vmcnt(0)+barrier drain). 54.5us = ~945 TF = structure ceiling.
//
// A = xb [8192][1024], B = wqb [3072][1024] (out[m][n]=sum_k A[m,k]B[n,k])
// Wave col map: col(nt) = (wave>>1)*32 + (nt&1)*16 + (nt>>1)*64 -> RoPE partner
// d^64 is acc[mt][nt^2][r] in the SAME lane => register-only RoPE. q/k epilogue
// round-trips bf16 through LDS for uint4 coalesced stores.
__global__ __launch_bounds__(256, 4)
void qkv_rope_kernel(const us* __restrict__ A, const us* __restrict__ B,
                     const float* __restrict__ ctab, const float* __restrict__ stab,
                     us* __restrict__ qb, us* __restrict__ kb, us* __restrict__ vtb) {
  __shared__ __align__(16) char smem_raw[128 * 136 * 2]; // 34816B
  us* sA = (us*)smem_raw;
  us* sB = sA + 128 * 64;
  us* sCus = (us*)smem_raw;

  const int tid = threadIdx.x;
  const int lane = tid & 63;
  const int wave = tid >> 6;
  const int l15 = lane & 15;
  const int lq = lane >> 4;
  const int m0 = blockIdx.x * 128;
  const int n0 = blockIdx.y * 128;
  const int wm = (wave & 1) * 64;
  const int wn2 = (wave >> 1) * 32;

  f32x4 acc[4][4] = {};

  for (int k0 = 0; k0 < 1024; k0 += 64) {
    for (int i = 0; i < 4; ++i) {
      int c = wave * 4 + i;
      int P = c * 64 + lane;           // 16B slot index
      int row = P >> 3;                // 8 slots per 64-el row
      int cb = (P & 7) ^ (row & 7);    // xor-swizzle
      gll16(A + (size_t)(m0 + row) * 1024 + k0 + cb * 8, sA + c * 512);
      gll16(B + (size_t)(n0 + row) * 1024 + k0 + cb * 8, sB + c * 512);
    }
    __syncthreads();
#pragma unroll
    for (int kk = 0; kk < 64; kk += 32) {
      const int cbr = (kk + lq * 8) >> 3;
      bf16x8 av[4], bv[4];
#pragma unroll
      for (int mt = 0; mt < 4; ++mt) {
        int m = wm + mt * 16 + l15;
        av[mt] = *(const bf16x8*)(sA + (m * 8 + (cbr ^ (m & 7))) * 8);
      }
#pragma unroll
      for (int nt = 0; nt < 4; ++nt) {
        int n = wn2 + (nt & 1) * 16 + (nt >> 1) * 64 + l15;
        bv[nt] = *(const bf16x8*)(sB + (n * 8 + (cbr ^ (n & 7))) * 8);
      }
#pragma unroll
      for (int mt = 0; mt < 4; ++mt)
#pragma unroll
        for (int nt = 0; nt < 4; ++nt)
          acc[mt][nt] = MFMA16(av[mt], bv[nt], acc[mt][nt]);
    }
    __syncthreads();
  }

  const int b = m0 >> 12;
  const int t0 = m0 & 4095;
  const int which = blockIdx.y >> 3;
  const int h = blockIdx.y & 7;

  if (which < 2) {
    // register RoPE -> bf16 LDS tile (ld=136: rows 16B-aligned) -> uint4 stores
    us* outp = (which == 0) ? qb : kb;
    const size_t obase = ((size_t)(b * 8 + h)) * 4096 * 128;
#pragma unroll
    for (int mt = 0; mt < 4; ++mt)
#pragma unroll
      for (int r = 0; r < 4; ++r) {
        const int row = wm + mt * 16 + lq * 4 + r;
        const int tg = t0 + row;
        const float* cp = ctab + tg * 64 + wn2 + l15;
        const float* sp = stab + tg * 64 + wn2 + l15;
        const float c0 = cp[0], c1 = cp[16], s0 = sp[0], s1 = sp[16];
#pragma unroll
        for (int nt = 0; nt < 4; ++nt) {
          float xv = acc[mt][nt][r];
          float xp = acc[mt][nt ^ 2][r];
          float rot = (nt < 2) ? -xp : xp;
          float y = xv * ((nt & 1) ? c1 : c0) + rot * ((nt & 1) ? s1 : s0);
          sCus[row * 136 + wn2 + (nt & 1) * 16 + (nt >> 1) * 64 + l15] = f2bf(y);
        }
      }
    __syncthreads();
    for (int r = 0; r < 8; ++r) {
      int row = (tid >> 4) + r * 16;
      int col = (tid & 15) * 8;
      uint4 v = *(const uint4*)(sCus + row * 136 + col);
      *(uint4*)(outp + obase + (size_t)(t0 + row) * 128 + col) = v;
    }
  } else {
    // V: bf16 LDS transpose, ld=130 (odd stride -> ~4-way column reads)
#pragma unroll
    for (int mt = 0; mt < 4; ++mt)
#pragma unroll
      for (int nt = 0; nt < 4; ++nt) {
        const int col = wn2 + (nt & 1) * 16 + (nt >> 1) * 64 + l15;
#pragma unroll
        for (int r = 0; r < 4; ++r)
          sCus[(wm + mt * 16 + lq * 4 + r) * 130 + col] = f2bf(acc[mt][nt][r]);
      }
    __syncthreads();
    for (int r = 0; r < 8; ++r) {
      int d = (tid >> 4) + r * 16;
      int tl0 = (tid & 15) * 8;
      union { us u[8]; uint4 v; } tmp;
#pragma unroll
      for (int j = 0; j < 8; ++j)
        tmp.u[j] = sCus[(tl0 + j) * 130 + d];
      *(uint4*)(vtb + ((size_t)((b * 8 + h) * 128 + d)) * 4096 + t0 + tl0) = tmp.v;
    }
  }
}

// --------------------------------------------------- flash attention --------
// R8: R4 flash structure restored EXACTLY (256 thr, 4 waves x 32 q-rows,
// QBLK=128, KVBLK=64 dbuf, 80KB LDS, 2 blocks/CU). R7 (8 waves x 16 rows)
// regressed +12us: per-tile LDS reads doubled (each wave reads full K,V tile
// regardless of rows owned) — rows/wave is the LDS-traffic knob and 64
// rows/wave costs ~244 regs (spill risk). ONE change vs R4: XCD-aware 1-D
// grid swizzle (T1). Accounting shows flash is HBM-refetch-bound (~160MB
// fetched vs 4MB/head resident; R5's 2x refetch ran BW-saturated at 3.6TB/s).
// Old grid put consecutive qx (80% K/V window overlap) on different XCDs ->
// per-XCD concurrent footprint ~64MB over 4MB L2 -> no reuse. New decode
// h=L&7, qx=(L>>3)&31, b=L>>8 puts ALL blocks of head h on XCD h (L%8):
// footprint 8MB -> overlapping windows hit L2.
// sP 128x64 XOR-block-swizzled; no running max (window scores bounded);
// l via 9th PV column against all-ones B-frag.
// MASK: 0=none, 1=window-low (first TWO tiles, t0>=512), 2=causal (last TWO).
template <int MASK>
__device__ __forceinline__ void p_write(f32x4 (&s)[2][4], us* __restrict__ sP,
                                        int t0, int tj0, int wm2, int lq, int l15) {
  const float C2 = 0.08838834764831845f * 1.4426950408889634f; // scale * log2(e)
#pragma unroll
  for (int mt = 0; mt < 2; ++mt)
#pragma unroll
    for (int nt = 0; nt < 4; ++nt) {
      const int jg = tj0 + nt * 16 + l15;
      const int cb = (nt * 16 + l15) >> 3; // 16B col-block 0..7
      const int co = l15 & 7;
#pragma unroll
      for (int r = 0; r < 4; ++r) {
        const int rowl = wm2 + mt * 16 + lq * 4 + r;
        float v = s[mt][nt][r];
        if (MASK == 1) v = (jg + 512 >= t0 + rowl) ? v : -3.0e38f;
        if (MASK == 2) v = (jg <= t0 + rowl) ? v : -3.0e38f;
        sP[rowl * 64 + ((cb ^ (rowl & 7)) * 8) + co] = f2bf(exp2f(v * C2));
      }
    }
}

// grid 512 x 256 thr = 2 blocks/CU, zero tail. (256,2): cap 256 regs/wave,
// demand ~186 -> no spill.
__global__ __launch_bounds__(256, 2)
void flash_kernel(const us* __restrict__ qg, const us* __restrict__ kg,
                  const us* __restrict__ vg, us* __restrict__ ao) {
  __shared__ us smem[40960]; // 81920 B total = 160KB/2 exactly
  us* sK = smem;             // dbuf 2 x (64 j x 128 d) swizzled
  us* sV = smem + 16384;     // dbuf 2 x (128 d x 64 j) swizzled (V^T)
  us* sP = smem + 32768;     // 128 x 64, XOR-block swizzle on (row&7)

  const int tid = threadIdx.x;
  const int lane = tid & 63;
  const int wave = tid >> 6;
  const int l15 = lane & 15;
  const int lq = lane >> 4;
  // XCD swizzle decode: XCD ~= L%8 -> all blocks of head h co-located
  const int L = blockIdx.x;
  const int h = L & 7;
  const int qx = (L >> 3) & 31;
  const int b = L >> 8;
  const int t0 = qx * 128;
  const size_t bh = (size_t)(b * 8 + h);
  const int wm2 = wave * 32;

  // Q fragments direct to registers (A-layout: A[m=lane&15][k=lq*8+j])
  bf16x8 qf[2][4];
#pragma unroll
  for (int mt = 0; mt < 2; ++mt)
#pragma unroll
    for (int ks = 0; ks < 4; ++ks)
      qf[mt][ks] = *(const bf16x8*)(qg + (bh * 4096 + t0 + wm2 + mt * 16 + l15) * 128 +
                                    ks * 32 + lq * 8);

  // all-ones B-fragment for the row-sum column
  union { us u[8]; bf16x8 v; } one_u;
#pragma unroll
  for (int i = 0; i < 8; ++i) one_u.u[i] = 0x3F80;
  const bf16x8 vone = one_u.v;

  f32x4 o[2][9] = {}; // [mt][0..7]=O columns, [mt][8]=row-sum l

  const int lo = t0 - 512;
  const int jtmin = (lo <= 0) ? 0 : (lo >> 6);
  const int jtmax = (t0 + 127) >> 6;
  const bool wmask = (t0 >= 512);

  auto stage = [&](int jt, int buf) {
    const int tj0 = jt * 64;
    us* dK = sK + buf * 8192;
    us* dV = sV + buf * 8192;
    for (int i = 0; i < 4; ++i) {
      int c = wave * 4 + i;
      int P = c * 64 + lane;
      int rowK = P >> 4;                 // 16 slots per 128-el row
      int cbK = (P & 15) ^ (rowK & 15);
      gll16(kg + (bh * 4096 + tj0 + rowK) * 128 + cbK * 8, dK + c * 512);
      int rowV = P >> 3;                 // 8 slots per 64-el row
      int cbV = (P & 7) ^ (rowV & 7);
      gll16(vg + (bh * 128 + rowV) * 4096 + tj0 + cbV * 8, dV + c * 512);
    }
  };

  stage(jtmin, 0);
  int cur = 0;

  for (int jt = jtmin; jt <= jtmax; ++jt) {
    __syncthreads(); // drains prefetch of buf[cur] (issued a full tile ago)
    if (jt < jtmax) stage(jt + 1, cur ^ 1);

    const int tj0 = jt * 64;
    const us* sKc = sK + cur * 8192;
    const us* sVc = sV + cur * 8192;

    // S = Q K^T  (each wave: 32 q-rows x 64 keys)
    f32x4 s[2][4] = {};
#pragma unroll
    for (int ks = 0; ks < 4; ++ks) {
      const int cbr = ks * 4 + lq;
#pragma unroll
      for (int nt = 0; nt < 4; ++nt) {
        int n = nt * 16 + l15;
        bf16x8 bk = *(const bf16x8*)(sKc + (n * 16 + (cbr ^ (n & 15))) * 8);
#pragma unroll
        for (int mt = 0; mt < 2; ++mt)
          s[mt][nt] = MFMA16(qf[mt][ks], bk, s[mt][nt]);
      }
    }

    // P = exp2(S*C2) with mask -> sP (own rows; no cross-lane ops, no barrier)
    if (jt >= jtmax - 1)               p_write<2>(s, sP, t0, tj0, wm2, lq, l15);
    else if (wmask && jt <= jtmin + 1) p_write<1>(s, sP, t0, tj0, wm2, lq, l15);
    else                               p_write<0>(s, sP, t0, tj0, wm2, lq, l15);

    // O += P V ; l += P 1  (A = sP own rows; in-order DS pipe covers RAW)
#pragma unroll
    for (int ks = 0; ks < 2; ++ks) {
#pragma unroll
      for (int mt = 0; mt < 2; ++mt) {
        bf16x8 ap = *(const bf16x8*)(sP + (wm2 + mt * 16 + l15) * 64 +
                                     (((ks * 4 + lq) ^ (l15 & 7)) * 8));
#pragma unroll
        for (int dt = 0; dt < 8; ++dt) {
          int dd = dt * 16 + l15;
          bf16x8 bv = *(const bf16x8*)(sVc + (dd * 8 + ((ks * 4 + lq) ^ (dd & 7))) * 8);
          o[mt][dt] = MFMA16(ap, bv, o[mt][dt]);
        }
        o[mt][8] = MFMA16(ap, vone, o[mt][8]);
      }
    }
    cur ^= 1;
  }

  // epilogue: O/l -> ao [b*4096+t][h*128+d] bf16
#pragma unroll
  for (int mt = 0; mt < 2; ++mt)
#pragma unroll
    for (int r = 0; r < 4; ++r) {
      const float inv = 1.0f / o[mt][8][r];
      const int rowl = wm2 + mt * 16 + lq * 4 + r;
      const size_t base = ((size_t)b * 4096 + t0 + rowl) * 1024 + h * 128;
#pragma unroll
      for (int dt = 0; dt < 8; ++dt)
        ao[base + dt * 16 + l15] = f2bf(o[mt][dt][r] * inv);
    }
}

// ------------------------------------------------ GEMM3: out = ao @ w_o^T ---
__global__ __launch_bounds__(256, 2)
void out_proj_kernel(const us* __restrict__ A, const us* __restrict__ B, float* __restrict__ C) {
  __shared__ us sA[128 * 64];
  __shared__ us sB[128 * 64];
  const int tid = threadIdx.x;
  const int lane = tid & 63;
  const int wave = tid >> 6;
  const int l15 = lane & 15;
  const int lq = lane >> 4;
  const int m0 = blockIdx.x * 128;
  const int n0 = blockIdx.y * 128;
  const int wm = (wave & 1) * 64;
  const int wn = (wave >> 1) * 64;
  f32x4 acc[4][4] = {};
  for (int k0 = 0; k0 < 1024; k0 += 64) {
    for (int i = 0; i < 4; ++i) {
      int c = wave * 4 + i;
      int P = c * 64 + lane;
      int row = P >> 3;
      int cb = (P & 7) ^ (row & 7);
      gll16(A + (size_t)(m0 + row) * 1024 + k0 + cb * 8, sA + c * 512);
      gll16(B + (size_t)(n0 + row) * 1024 + k0 + cb * 8, sB + c * 512);
    }
    __syncthreads();
#pragma unroll
    for (int kk = 0; kk < 64; kk += 32) {
      const int cbr = (kk + lq * 8) >> 3;
      bf16x8 av[4], bv[4];
#pragma unroll
      for (int mt = 0; mt < 4; ++mt) {
        int m = wm + mt * 16 + l15;
        av[mt] = *(const bf16x8*)(sA + (m * 8 + (cbr ^ (m & 7))) * 8);
      }
#pragma unroll
      for (int nt = 0; nt < 4; ++nt) {
        int n = wn + nt * 16 + l15;
        bv[nt] = *(const bf16x8*)(sB + (n * 8 + (cbr ^ (n & 7))) * 8);
      }
#pragma unroll
      for (int mt = 0; mt < 4; ++mt)
#pragma unroll
        for (int nt = 0; nt < 4; ++nt)
          acc[mt][nt] = MFMA16(av[mt], bv[nt], acc[mt][nt]);
    }
    __syncthreads();
  }
#pragma unroll
  for (int mt = 0; mt < 4; ++mt)
#pragma unroll
    for (int nt = 0; nt < 4; ++nt)
#pragma unroll
      for (int r = 0; r < 4; ++r)
        C[(size_t)(m0 + wm + mt * 16 + lq * 4 + r) * 1024 + (n0 + wn + nt * 16 + l15)] =
            acc[mt][nt][r];
}

// ---------------------------------------------------------------- launch ----
extern "C" void kernel_launch(void* const* d_in, const int* in_sizes, int n_in,
                              void* d_out, int out_size, void* d_ws, size_t ws_size,
                              hipStream_t stream) {
  const float* x     = (const float*)d_in[0];  // [2,4096,1024]
  const float* w_qkv = (const float*)d_in[1];  // [3072,1024]
  const float* w_o   = (const float*)d_in[2];  // [1024,1024]
  float* out = (float*)d_out;                  // [2,4096,1024] fp32

  us* xb  = (us*)d_ws;                          // 8192*1024
  us* wqb = xb  + (size_t)8192 * 1024;          // 3072*1024
  us* wob = wqb + (size_t)3072 * 1024;          // 1024*1024
  us* qb  = wob + (size_t)1024 * 1024;          // [2][8][4096][128]
  us* kb  = qb  + (size_t)2 * 8 * 4096 * 128;
  us* vtb = kb  + (size_t)2 * 8 * 4096 * 128;   // [2][8][128][4096]
  us* aob = vtb + (size_t)2 * 8 * 4096 * 128;   // 8192*1024
  float* ctab = (float*)(aob + (size_t)8192 * 1024); // [4096][64]
  float* stab = ctab + (size_t)4096 * 64;

  prep_kernel<<<13312, 256, 0, stream>>>(x, w_qkv, w_o, xb, wqb, wob, ctab, stab);
  qkv_rope_kernel<<<dim3(64, 24), 256, 0, stream>>>(xb, wqb, ctab, stab, qb, kb, vtb);
  flash_kernel<<<512, 256, 0, stream>>>(qb, kb, vtb, aob);
  out_proj_kernel<<<dim3(64, 8), 256, 0, stream>>>(aob, wob, out);
}

// Round 9
// 205.517 us; speedup vs baseline: 1.2095x; 1.0051x over previous
//
#include <hip/hip_runtime.h>
#include <hip/hip_bf16.h>

typedef unsigned short us;
typedef __attribute__((ext_vector_type(8))) __bf16 bf16x8;
typedef __attribute__((ext_vector_type(4))) float f32x4;

#define MFMA16(a, b, c) __builtin_amdgcn_mfma_f32_16x16x32_bf16(a, b, c, 0, 0, 0)

static __device__ __forceinline__ us f2bf(float f) {
  __hip_bfloat16 h = __float2bfloat16(f);
  return __builtin_bit_cast(us, h);
}

// async global->LDS, 16B per lane; LDS dest is wave-uniform base + lane*16
static __device__ __forceinline__ void gll16(const us* g, us* l) {
  __builtin_amdgcn_global_load_lds((const __attribute__((address_space(1))) void*)g,
                                   (__attribute__((address_space(3))) void*)l,
                                   16, 0, 0);
}

// ------------------------------------------------ prep: casts + rope table --
// blocks [0,8192): cast x; [8192,11264): cast w_qkv; [11264,12288): cast w_o;
// [12288,13312): rope table (4096 x 64).
__global__ void prep_kernel(const float* __restrict__ x, const float* __restrict__ wq,
                            const float* __restrict__ wo, us* __restrict__ xb,
                            us* __restrict__ wqb, us* __restrict__ wob,
                            float* __restrict__ ct, float* __restrict__ st) {
  const int blk = blockIdx.x;
  const int tid = threadIdx.x;
  if (blk < 12288) {
    const float* in;
    us* out;
    int i;
    if (blk < 8192)      { in = x;  out = xb;  i = blk * 256 + tid; }
    else if (blk < 11264){ in = wq; out = wqb; i = (blk - 8192) * 256 + tid; }
    else                 { in = wo; out = wob; i = (blk - 11264) * 256 + tid; }
    float4 v = ((const float4*)in)[i];
    ushort4 o;
    o.x = f2bf(v.x); o.y = f2bf(v.y); o.z = f2bf(v.z); o.w = f2bf(v.w);
    ((ushort4*)out)[i] = o;
  } else {
    int i = (blk - 12288) * 256 + tid;
    int t = i >> 6, d = i & 63;
    float ang = (float)t * exp2f((float)d * -0.20762050593046014f);
    float s, c;
    sincosf(ang, &s, &c);
    ct[i] = c;
    st[i] = s;
  }
}

// ------------------------------------------- GEMM1: qkv + RoPE + scatter ----
// R4-winning version, unchanged: 128^2 m97 structure, bf16 ld=130 V-epilogue
// -> 34.8KB LDS -> 4 blocks/CU (2->4 was +19%: cross-block waves hide each
// K-step's vmcnt(0)+barrier drain). 54.5us = ~945 TF = structure ceiling.
//
// A = xb [8192][1024], B = wqb [3072][1024] (out[m][n]=sum_k A[m,k]B[n,k])
// Wave col map: col(nt) = (wave>>1)*32 + (nt&1)*16 + (nt>>1)*64 -> RoPE partner
// d^64 is acc[mt][nt^2][r] in the SAME lane => register-only RoPE. q/k epilogue
// round-trips bf16 through LDS for uint4 coalesced stores.
__global__ __launch_bounds__(256, 4)
void qkv_rope_kernel(const us* __restrict__ A, const us* __restrict__ B,
                     const float* __restrict__ ctab, const float* __restrict__ stab,
                     us* __restrict__ qb, us* __restrict__ kb, us* __restrict__ vtb) {
  __shared__ __align__(16) char smem_raw[128 * 136 * 2]; // 34816B
  us* sA = (us*)smem_raw;
  us* sB = sA + 128 * 64;
  us* sCus = (us*)smem_raw;

  const int tid = threadIdx.x;
  const int lane = tid & 63;
  const int wave = tid >> 6;
  const int l15 = lane & 15;
  const int lq = lane >> 4;
  const int m0 = blockIdx.x * 128;
  const int n0 = blockIdx.y * 128;
  const int wm = (wave & 1) * 64;
  const int wn2 = (wave >> 1) * 32;

  f32x4 acc[4][4] = {};

  for (int k0 = 0; k0 < 1024; k0 += 64) {
    for (int i = 0; i < 4; ++i) {
      int c = wave * 4 + i;
      int P = c * 64 + lane;           // 16B slot index
      int row = P >> 3;                // 8 slots per 64-el row
      int cb = (P & 7) ^ (row & 7);    // xor-swizzle
      gll16(A + (size_t)(m0 + row) * 1024 + k0 + cb * 8, sA + c * 512);
      gll16(B + (size_t)(n0 + row) * 1024 + k0 + cb * 8, sB + c * 512);
    }
    __syncthreads();
#pragma unroll
    for (int kk = 0; kk < 64; kk += 32) {
      const int cbr = (kk + lq * 8) >> 3;
      bf16x8 av[4], bv[4];
#pragma unroll
      for (int mt = 0; mt < 4; ++mt) {
        int m = wm + mt * 16 + l15;
        av[mt] = *(const bf16x8*)(sA + (m * 8 + (cbr ^ (m & 7))) * 8);
      }
#pragma unroll
      for (int nt = 0; nt < 4; ++nt) {
        int n = wn2 + (nt & 1) * 16 + (nt >> 1) * 64 + l15;
        bv[nt] = *(const bf16x8*)(sB + (n * 8 + (cbr ^ (n & 7))) * 8);
      }
#pragma unroll
      for (int mt = 0; mt < 4; ++mt)
#pragma unroll
        for (int nt = 0; nt < 4; ++nt)
          acc[mt][nt] = MFMA16(av[mt], bv[nt], acc[mt][nt]);
    }
    __syncthreads();
  }

  const int b = m0 >> 12;
  const int t0 = m0 & 4095;
  const int which = blockIdx.y >> 3;
  const int h = blockIdx.y & 7;

  if (which < 2) {
    // register RoPE -> bf16 LDS tile (ld=136: rows 16B-aligned) -> uint4 stores
    us* outp = (which == 0) ? qb : kb;
    const size_t obase = ((size_t)(b * 8 + h)) * 4096 * 128;
#pragma unroll
    for (int mt = 0; mt < 4; ++mt)
#pragma unroll
      for (int r = 0; r < 4; ++r) {
        const int row = wm + mt * 16 + lq * 4 + r;
        const int tg = t0 + row;
        const float* cp = ctab + tg * 64 + wn2 + l15;
        const float* sp = stab + tg * 64 + wn2 + l15;
        const float c0 = cp[0], c1 = cp[16], s0 = sp[0], s1 = sp[16];
#pragma unroll
        for (int nt = 0; nt < 4; ++nt) {
          float xv = acc[mt][nt][r];
          float xp = acc[mt][nt ^ 2][r];
          float rot = (nt < 2) ? -xp : xp;
          float y = xv * ((nt & 1) ? c1 : c0) + rot * ((nt & 1) ? s1 : s0);
          sCus[row * 136 + wn2 + (nt & 1) * 16 + (nt >> 1) * 64 + l15] = f2bf(y);
        }
      }
    __syncthreads();
    for (int r = 0; r < 8; ++r) {
      int row = (tid >> 4) + r * 16;
      int col = (tid & 15) * 8;
      uint4 v = *(const uint4*)(sCus + row * 136 + col);
      *(uint4*)(outp + obase + (size_t)(t0 + row) * 128 + col) = v;
    }
  } else {
    // V: bf16 LDS transpose, ld=130 (odd stride -> ~4-way column reads)
#pragma unroll
    for (int mt = 0; mt < 4; ++mt)
#pragma unroll
      for (int nt = 0; nt < 4; ++nt) {
        const int col = wn2 + (nt & 1) * 16 + (nt >> 1) * 64 + l15;
#pragma unroll
        for (int r = 0; r < 4; ++r)
          sCus[(wm + mt * 16 + lq * 4 + r) * 130 + col] = f2bf(acc[mt][nt][r]);
      }
    __syncthreads();
    for (int r = 0; r < 8; ++r) {
      int d = (tid >> 4) + r * 16;
      int tl0 = (tid & 15) * 8;
      union { us u[8]; uint4 v; } tmp;
#pragma unroll
      for (int j = 0; j < 8; ++j)
        tmp.u[j] = sCus[(tl0 + j) * 130 + d];
      *(uint4*)(vtb + ((size_t)((b * 8 + h) * 128 + d)) * 4096 + t0 + tl0) = tmp.v;
    }
  }
}

// --------------------------------------------------- flash attention --------
// R9: R4 flash restored EXACTLY (3-D grid, default block mapping). R8's
// XCD-swizzle (all of head h on XCD h) was null-to-negative (-4.5us):
// 4MB KV + Q/ao streams on a 4MB L2 = marginal fit -> thrash. Flash is at
// its structural floor: ~153MB fetch at ~4.4TB/s effective (70% of
// achievable), 5x KV refetch required by QBLK=128 tiling (bigger QBLK ->
// LDS/occupancy cliff; smaller -> 2x fetch (R5); L2 blocking -> null (R8)).
// 128 q-rows/block (32/wave), 64-key dbuf tiles, 1 barrier/tile. sP is a
// dedicated XOR-block-swizzled ld=64 region (LDS exactly 80KB -> 2/CU).
// No running max (window scores bounded); l via 9th PV column (all-ones B).
// MASK: 0=none, 1=window-low (first TWO tiles, t0>=512), 2=causal (last TWO).
template <int MASK>
__device__ __forceinline__ void p_write(f32x4 (&s)[2][4], us* __restrict__ sP,
                                        int t0, int tj0, int wm2, int lq, int l15) {
  const float C2 = 0.08838834764831845f * 1.4426950408889634f; // scale * log2(e)
#pragma unroll
  for (int mt = 0; mt < 2; ++mt)
#pragma unroll
    for (int nt = 0; nt < 4; ++nt) {
      const int jg = tj0 + nt * 16 + l15;
      const int cb = (nt * 16 + l15) >> 3; // 16B col-block 0..7
      const int co = l15 & 7;
#pragma unroll
      for (int r = 0; r < 4; ++r) {
        const int rowl = wm2 + mt * 16 + lq * 4 + r;
        float v = s[mt][nt][r];
        if (MASK == 1) v = (jg + 512 >= t0 + rowl) ? v : -3.0e38f;
        if (MASK == 2) v = (jg <= t0 + rowl) ? v : -3.0e38f;
        sP[rowl * 64 + ((cb ^ (rowl & 7)) * 8) + co] = f2bf(exp2f(v * C2));
      }
    }
}

// grid (qx=32, h=8, b=2) = 512 blocks = exactly 2/CU x 256 CUs, zero tail.
// (256,2): cap 256 regs/wave, demand ~186 -> no spill.
__global__ __launch_bounds__(256, 2)
void flash_kernel(const us* __restrict__ qg, const us* __restrict__ kg,
                  const us* __restrict__ vg, us* __restrict__ ao) {
  __shared__ us smem[40960]; // 81920 B total = 160KB/2 exactly
  us* sK = smem;             // dbuf 2 x (64 j x 128 d) swizzled
  us* sV = smem + 16384;     // dbuf 2 x (128 d x 64 j) swizzled (V^T)
  us* sP = smem + 32768;     // 128 x 64, XOR-block swizzle on (row&7)

  const int tid = threadIdx.x;
  const int lane = tid & 63;
  const int wave = tid >> 6;
  const int l15 = lane & 15;
  const int lq = lane >> 4;
  const int qx = blockIdx.x;
  const int h = blockIdx.y;
  const int b = blockIdx.z;
  const int t0 = qx * 128;
  const size_t bh = (size_t)(b * 8 + h);
  const int wm2 = wave * 32;

  // Q fragments direct to registers (A-layout: A[m=lane&15][k=lq*8+j])
  bf16x8 qf[2][4];
#pragma unroll
  for (int mt = 0; mt < 2; ++mt)
#pragma unroll
    for (int ks = 0; ks < 4; ++ks)
      qf[mt][ks] = *(const bf16x8*)(qg + (bh * 4096 + t0 + wm2 + mt * 16 + l15) * 128 +
                                    ks * 32 + lq * 8);

  // all-ones B-fragment for the row-sum column
  union { us u[8]; bf16x8 v; } one_u;
#pragma unroll
  for (int i = 0; i < 8; ++i) one_u.u[i] = 0x3F80;
  const bf16x8 vone = one_u.v;

  f32x4 o[2][9] = {}; // [mt][0..7]=O columns, [mt][8]=row-sum l

  const int lo = t0 - 512;
  const int jtmin = (lo <= 0) ? 0 : (lo >> 6);
  const int jtmax = (t0 + 127) >> 6;
  const bool wmask = (t0 >= 512);

  auto stage = [&](int jt, int buf) {
    const int tj0 = jt * 64;
    us* dK = sK + buf * 8192;
    us* dV = sV + buf * 8192;
    for (int i = 0; i < 4; ++i) {
      int c = wave * 4 + i;
      int P = c * 64 + lane;
      int rowK = P >> 4;                 // 16 slots per 128-el row
      int cbK = (P & 15) ^ (rowK & 15);
      gll16(kg + (bh * 4096 + tj0 + rowK) * 128 + cbK * 8, dK + c * 512);
      int rowV = P >> 3;                 // 8 slots per 64-el row
      int cbV = (P & 7) ^ (rowV & 7);
      gll16(vg + (bh * 128 + rowV) * 4096 + tj0 + cbV * 8, dV + c * 512);
    }
  };

  stage(jtmin, 0);
  int cur = 0;

  for (int jt = jtmin; jt <= jtmax; ++jt) {
    __syncthreads(); // drains prefetch of buf[cur] (issued a full tile ago)
    if (jt < jtmax) stage(jt + 1, cur ^ 1);

    const int tj0 = jt * 64;
    const us* sKc = sK + cur * 8192;
    const us* sVc = sV + cur * 8192;

    // S = Q K^T  (each wave: 32 q-rows x 64 keys)
    f32x4 s[2][4] = {};
#pragma unroll
    for (int ks = 0; ks < 4; ++ks) {
      const int cbr = ks * 4 + lq;
#pragma unroll
      for (int nt = 0; nt < 4; ++nt) {
        int n = nt * 16 + l15;
        bf16x8 bk = *(const bf16x8*)(sKc + (n * 16 + (cbr ^ (n & 15))) * 8);
#pragma unroll
        for (int mt = 0; mt < 2; ++mt)
          s[mt][nt] = MFMA16(qf[mt][ks], bk, s[mt][nt]);
      }
    }

    // P = exp2(S*C2) with mask -> sP (own rows; no cross-lane ops, no barrier)
    if (jt >= jtmax - 1)               p_write<2>(s, sP, t0, tj0, wm2, lq, l15);
    else if (wmask && jt <= jtmin + 1) p_write<1>(s, sP, t0, tj0, wm2, lq, l15);
    else                               p_write<0>(s, sP, t0, tj0, wm2, lq, l15);

    // O += P V ; l += P 1  (A = sP own rows; in-order DS pipe covers RAW)
#pragma unroll
    for (int ks = 0; ks < 2; ++ks) {
#pragma unroll
      for (int mt = 0; mt < 2; ++mt) {
        bf16x8 ap = *(const bf16x8*)(sP + (wm2 + mt * 16 + l15) * 64 +
                                     (((ks * 4 + lq) ^ (l15 & 7)) * 8));
#pragma unroll
        for (int dt = 0; dt < 8; ++dt) {
          int dd = dt * 16 + l15;
          bf16x8 bv = *(const bf16x8*)(sVc + (dd * 8 + ((ks * 4 + lq) ^ (dd & 7))) * 8);
          o[mt][dt] = MFMA16(ap, bv, o[mt][dt]);
        }
        o[mt][8] = MFMA16(ap, vone, o[mt][8]);
      }
    }
    cur ^= 1;
  }

  // epilogue: O/l -> ao [b*4096+t][h*128+d] bf16
#pragma unroll
  for (int mt = 0; mt < 2; ++mt)
#pragma unroll
    for (int r = 0; r < 4; ++r) {
      const float inv = 1.0f / o[mt][8][r];
      const int rowl = wm2 + mt * 16 + lq * 4 + r;
      const size_t base = ((size_t)b * 4096 + t0 + rowl) * 1024 + h * 128;
#pragma unroll
      for (int dt = 0; dt < 8; ++dt)
        ao[base + dt * 16 + l15] = f2bf(o[mt][dt][r] * inv);
    }
}

// ------------------------------------------------ GEMM3: out = ao @ w_o^T ---
// R9: 128x64 tiles (was 128x128). Grid (64,16)=1024 blocks = exactly 4/CU
// (was 512 = 2/CU in ONE round -> duration == per-block latency at 2/CU).
// R4 evidence: this structure's per-round latency drops with 4 blocks/CU
// (cross-block waves hide the per-K-step vmcnt(0)+barrier drain). LDS
// 24KB (sA 16K + sB 8K), acc[4][2] -> ~64 regs at (256,4), zero tail.
// A-panel re-reads double (16x) but aob (16.8MB) is L3-resident.
__global__ __launch_bounds__(256, 4)
void out_proj_kernel(const us* __restrict__ A, const us* __restrict__ B, float* __restrict__ C) {
  __shared__ us sA[128 * 64];
  __shared__ us sB[64 * 64];
  const int tid = threadIdx.x;
  const int lane = tid & 63;
  const int wave = tid >> 6;
  const int l15 = lane & 15;
  const int lq = lane >> 4;
  const int m0 = blockIdx.x * 128;
  const int n0 = blockIdx.y * 64;
  const int wm = (wave & 1) * 64;
  const int wn = (wave >> 1) * 32;
  f32x4 acc[4][2] = {};
  for (int k0 = 0; k0 < 1024; k0 += 64) {
    for (int i = 0; i < 4; ++i) {
      int c = wave * 4 + i;
      int P = c * 64 + lane;
      int row = P >> 3;
      int cb = (P & 7) ^ (row & 7);
      gll16(A + (size_t)(m0 + row) * 1024 + k0 + cb * 8, sA + c * 512);
    }
    for (int i = 0; i < 2; ++i) {
      int c = wave * 2 + i;
      int P = c * 64 + lane;
      int row = P >> 3;
      int cb = (P & 7) ^ (row & 7);
      gll16(B + (size_t)(n0 + row) * 1024 + k0 + cb * 8, sB + c * 512);
    }
    __syncthreads();
#pragma unroll
    for (int kk = 0; kk < 64; kk += 32) {
      const int cbr = (kk + lq * 8) >> 3;
      bf16x8 av[4], bv[2];
#pragma unroll
      for (int mt = 0; mt < 4; ++mt) {
        int m = wm + mt * 16 + l15;
        av[mt] = *(const bf16x8*)(sA + (m * 8 + (cbr ^ (m & 7))) * 8);
      }
#pragma unroll
      for (int nt = 0; nt < 2; ++nt) {
        int n = wn + nt * 16 + l15;
        bv[nt] = *(const bf16x8*)(sB + (n * 8 + (cbr ^ (n & 7))) * 8);
      }
#pragma unroll
      for (int mt = 0; mt < 4; ++mt)
#pragma unroll
        for (int nt = 0; nt < 2; ++nt)
          acc[mt][nt] = MFMA16(av[mt], bv[nt], acc[mt][nt]);
    }
    __syncthreads();
  }
#pragma unroll
  for (int mt = 0; mt < 4; ++mt)
#pragma unroll
    for (int nt = 0; nt < 2; ++nt)
#pragma unroll
      for (int r = 0; r < 4; ++r)
        C[(size_t)(m0 + wm + mt * 16 + lq * 4 + r) * 1024 + (n0 + wn + nt * 16 + l15)] =
            acc[mt][nt][r];
}

// ---------------------------------------------------------------- launch ----
extern "C" void kernel_launch(void* const* d_in, const int* in_sizes, int n_in,
                              void* d_out, int out_size, void* d_ws, size_t ws_size,
                              hipStream_t stream) {
  const float* x     = (const float*)d_in[0];  // [2,4096,1024]
  const float* w_qkv = (const float*)d_in[1];  // [3072,1024]
  const float* w_o   = (const float*)d_in[2];  // [1024,1024]
  float* out = (float*)d_out;                  // [2,4096,1024] fp32

  us* xb  = (us*)d_ws;                          // 8192*1024
  us* wqb = xb  + (size_t)8192 * 1024;          // 3072*1024
  us* wob = wqb + (size_t)3072 * 1024;          // 1024*1024
  us* qb  = wob + (size_t)1024 * 1024;          // [2][8][4096][128]
  us* kb  = qb  + (size_t)2 * 8 * 4096 * 128;
  us* vtb = kb  + (size_t)2 * 8 * 4096 * 128;   // [2][8][128][4096]
  us* aob = vtb + (size_t)2 * 8 * 4096 * 128;   // 8192*1024
  float* ctab = (float*)(aob + (size_t)8192 * 1024); // [4096][64]
  float* stab = ctab + (size_t)4096 * 64;

  prep_kernel<<<13312, 256, 0, stream>>>(x, w_qkv, w_o, xb, wqb, wob, ctab, stab);
  qkv_rope_kernel<<<dim3(64, 24), 256, 0, stream>>>(xb, wqb, ctab, stab, qb, kb, vtb);
  flash_kernel<<<dim3(32, 8, 2), 256, 0, stream>>>(qb, kb, vtb, aob);
  out_proj_kernel<<<dim3(64, 16), 256, 0, stream>>>(aob, wob, out);
}